// Round 18
// baseline (27.589 us; speedup 1.0000x reference)
//
#include <hip/hip_runtime.h>

// APLoss (r2d2 QAPLoss). B=2, H=W=32 -> N=M=1024/batch, D=128, 25 bins.
// u = 24*(1-sim); cumsum_k of triangular bins = clamp(k+1-u, 0, 1).
// R18 = R14/R17 champion (25.6us) with 1024-thread k_main blocks:
// 16 waves (4/SIMD, was 2) for latency cover; thread owns ONE p; hist
// splits each query across a wave pair (8 e each, 8 records/query).
//   k_main : S0 tile (8q x 1024p GEMM on desc2) -> on-the-fly bilinear
//            warp + histogram + AP  (256 blk x 1024 thr)
//   k_final: 256 partials -> out.

#define NQB 25

// DPP butterfly add over 16-lane rows (pure VALU, no LDS pipe).
template<int CTRL>
__device__ __forceinline__ float dppadd(float v) {
    int s = __builtin_amdgcn_update_dpp(0, __float_as_int(v), CTRL, 0xf, 0xf, true);
    return v + __int_as_float(s);
}
__device__ __forceinline__ float red16(float v) {
    v = dppadd<0xB1>(v);   // quad_perm xor1
    v = dppadd<0x4E>(v);   // quad_perm xor2
    v = dppadd<0x141>(v);  // row_half_mirror = xor7
    v = dppadd<0x140>(v);  // row_mirror      = xor15
    return v;              // every lane: its 16-lane-row sum
}

// ---- sim helpers: chunk = 8 consecutive c; thread owns one p ---------------
__device__ __forceinline__ void loadc(const float* __restrict__ dp, int ch,
                                      float* d)
{
    int cb = ch << 3;
#pragma unroll
    for (int i = 0; i < 8; i++) d[i] = dp[(size_t)(cb + i) << 10];
}
__device__ __forceinline__ void fmac(const float* __restrict__ d1, int ch,
                                     const float* d, float* a)
{
    int cb = ch << 3;
#pragma unroll
    for (int i = 0; i < 8; i++) {
        const float* qp = d1 + ((size_t)(cb + i) << 10);
#pragma unroll
        for (int qq = 0; qq < 8; qq++) {
            float qv = qp[qq];   // wave-uniform -> scalar load
            a[qq] = fmaf(qv, d[i], a[qq]);
        }
    }
}

// ---- K1: fused S0 GEMM + warp + histogram + AP; 8 q x all p, 1024 thr ------
__global__ __launch_bounds__(1024) void k_main(const float* __restrict__ desc1,
                                               const float* __restrict__ desc2,
                                               const float* __restrict__ grd,
                                               const int* __restrict__ label,
                                               float* __restrict__ appart)
{
    __shared__ float s[8][1024];     // S0 tile: 8 queries x 1024 grid positions
    __shared__ float CNs[8][8][NQB]; // 8 records/query (4 lane-groups x 2 halves)
    __shared__ float CRs[8][8][NQB];
    __shared__ float apb[8];

    int tid = threadIdx.x;
    int qg0 = blockIdx.x << 3;      // global query base (b*1024 + n0)
    int b = qg0 >> 10;
    int n0 = qg0 & 1023;

    // ---- hist roles: wave pair per query; prefetch labels + grid coords ----
    int w = tid >> 6, l = tid & 63;
    int q = w >> 1, h = w & 1;      // query, e-half
    int e0 = h << 3;
    const int* lp = label + ((size_t)(qg0 + q) << 10) + (e0 << 6) + l;
    int lv[8];
#pragma unroll
    for (int e = 0; e < 8; e++) lv[e] = lp[(size_t)(e << 6)];
    const float2* gp = (const float2*)grd + ((size_t)b << 10) + (e0 << 6) + l;
    float2 gv[8];
#pragma unroll
    for (int e = 0; e < 8; e++) gv[e] = gp[(size_t)(e << 6)];

    // ---- S0 GEMM phase: thread owns p = tid; 2-deep ping-pong, 16 chunks ---
    const float* d1 = desc1 + ((size_t)b << 17) + n0;  // q-row: d1[(c<<10)+qq]
    const float* dp = desc2 + ((size_t)b << 17) + tid; // p-col: dp[c<<10]

    float a[8];
#pragma unroll
    for (int qq = 0; qq < 8; qq++) a[qq] = 0.f;

    float dA[8], dB[8];
    loadc(dp, 0, dA);
    for (int ch = 0; ch < 16; ch += 2) {
        loadc(dp, ch + 1, dB);          // issue next chunk
        fmac(d1, ch, dA, a);            // consume current
        if (ch + 2 < 16) loadc(dp, ch + 2, dA);
        fmac(d1, ch + 1, dB, a);
    }
#pragma unroll
    for (int qq = 0; qq < 8; qq++) s[qq][tid] = a[qq];
    __syncthreads();

    // ---- histogram with on-the-fly bilinear warp (verbatim R14 warp code) --
    float CN[NQB], CR[NQB];
#pragma unroll
    for (int k = 0; k < NQB; k++) { CN[k] = 0.f; CR[k] = 0.f; }
    const float* sq = s[q];
#pragma unroll
    for (int e = 0; e < 8; e++) {
        float gx = gv[e].x, gy = gv[e].y;
        float fx = ((gx + 1.f) * 32.f - 1.f) * 0.5f;
        float fy = ((gy + 1.f) * 32.f - 1.f) * 0.5f;
        float x0f = floorf(fx), y0f = floorf(fy);
        float wx1 = fx - x0f, wy1 = fy - y0f;
        float wx0 = 1.f - wx1, wy0 = 1.f - wy1;
        int x0 = (int)x0f, y0 = (int)y0f;
        int x1 = x0 + 1, y1 = y0 + 1;
        bool bx0 = (unsigned)x0 < 32u, bx1 = (unsigned)x1 < 32u;
        bool by0 = (unsigned)y0 < 32u, by1 = (unsigned)y1 < 32u;
        float w00 = (by0 && bx0) ? wy0 * wx0 : 0.f;
        float w01 = (by0 && bx1) ? wy0 * wx1 : 0.f;
        float w10 = (by1 && bx0) ? wy1 * wx0 : 0.f;
        float w11 = (by1 && bx1) ? wy1 * wx1 : 0.f;
        int xc0 = min(max(x0, 0), 31), xc1 = min(max(x1, 0), 31);
        int yc0 = min(max(y0, 0), 31), yc1 = min(max(y1, 0), 31);
        float sv = w00 * sq[(yc0 << 5) + xc0];
        sv = fmaf(w01, sq[(yc0 << 5) + xc1], sv);
        sv = fmaf(w10, sq[(yc1 << 5) + xc0], sv);
        sv = fmaf(w11, sq[(yc1 << 5) + xc1], sv);

        float u = fmaf(-24.f, sv, 24.f);
        float lfv = (float)lv[e];
#pragma unroll
        for (int k = 0; k < NQB; k++) {
            float t = fminf(fmaxf((float)(k + 1) - u, 0.f), 1.f);  // v_med3
            CN[k] += t;
            CR[k] = fmaf(lfv, t, CR[k]);
        }
    }
#pragma unroll
    for (int k = 0; k < NQB; k++) { CN[k] = red16(CN[k]); CR[k] = red16(CR[k]); }
    if ((l & 15) == 0) {
        int rec = (h << 2) + (l >> 4);
#pragma unroll
        for (int k = 0; k < NQB; k++) { CNs[q][rec][k] = CN[k]; CRs[q][rec][k] = CR[k]; }
    }
    __syncthreads();

    // ---- AP per query (8 threads, fixed-order combine), block sum ----
    if (tid < 8) {
        float ap = 0.f, prev = 0.f;
#pragma unroll
        for (int k = 0; k < NQB; k++) {
            float cn = 0.f, cr = 0.f;
#pragma unroll
            for (int r = 0; r < 8; r++) { cn += CNs[tid][r][k]; cr += CRs[tid][r][k]; }
            float pr = cr / (1e-16f + cn);
            ap += pr * (cr - prev);
            prev = cr;
        }
        apb[tid] = ap / prev;
    }
    __syncthreads();
    if (tid == 0) {
        float v = 0.f;
#pragma unroll
        for (int q2 = 0; q2 < 8; q2++) v += apb[q2];
        appart[blockIdx.x] = v;
    }
}

// ---- K2: final reduce of per-block sums -> d_out ---------------------------
__global__ __launch_bounds__(256) void k_final(const float* __restrict__ appart,
                                               float* __restrict__ out,
                                               int nb, float invn)
{
    int tid = threadIdx.x;
    float v = 0.f;
    for (int i = tid; i < nb; i += 256) v += appart[i];
    for (int off = 32; off; off >>= 1) v += __shfl_xor(v, off, 64);
    __shared__ float wsum[4];
    if ((tid & 63) == 0) wsum[tid >> 6] = v;
    __syncthreads();
    if (tid == 0) out[0] = (wsum[0] + wsum[1] + wsum[2] + wsum[3]) * invn;
}

extern "C" void kernel_launch(void* const* d_in, const int* in_sizes, int n_in,
                              void* d_out, int out_size, void* d_ws, size_t ws_size,
                              hipStream_t stream)
{
    const float* desc1 = (const float*)d_in[0];
    const float* desc2 = (const float*)d_in[1];
    // d_in[2] = reliability: unused by the reference output
    const float* grd   = (const float*)d_in[3];
    const int*   label = (const int*)d_in[4];

    int B = in_sizes[0] / (128 * 1024);
    int npos = B * 1024;
    int nblk = npos / 8;

    float* ws = (float*)d_ws;
    float* appart = ws;                 // nblk floats
    float* out = (float*)d_out;

    k_main<<<nblk, 1024, 0, stream>>>(desc1, desc2, grd, label, appart);
    k_final<<<1, 256, 0, stream>>>(appart, out, nblk, 1.f / (float)npos);
}